// Round 1
// baseline (414.893 us; speedup 1.0000x reference)
//
#include <hip/hip_runtime.h>

// Problem constants (from reference): B=8, S=4096, H=8, D=128
// MAX_TOTAL = B*S = 32768 output cache rows per cache.
// Each row = H*D = 1024 floats = 256 float4 = 4 KB, contiguous.
#define BB 8
#define SS 4096
#define ROW_F4 256            // float4 elements per row (H*D/4)
#define MAX_TOTAL 32768
#define NTASKS (2 * MAX_TOTAL) // k rows then v rows

__global__ __launch_bounds__(256) void pack_kv_kernel(
    const float4* __restrict__ kin,
    const float4* __restrict__ vin,
    const int*    __restrict__ seq,
    float4* __restrict__ kout,
    float4* __restrict__ vout,
    float*  __restrict__ meta)   // meta[0..7]=seq_lens, meta[8..16]=cumsum(9)
{
    // Tiny cumsum in registers (uniform across all threads; seq is 8 ints, L2-hot)
    int cum[BB + 1];
    cum[0] = 0;
#pragma unroll
    for (int b = 0; b < BB; ++b) cum[b + 1] = cum[b] + seq[b];

    // Block 0 also emits the scalar outputs (as float values — d_out is a
    // single flat float32 buffer covering the whole output tuple).
    if (blockIdx.x == 0 && threadIdx.x < (BB + BB + 1)) {
        int t = threadIdx.x;
        if (t < BB) meta[t] = (float)seq[t];
        else        meta[t] = (float)cum[t - BB];   // meta[8+i] = cum[i]
    }

    const float4 zero = make_float4(0.f, 0.f, 0.f, 0.f);
    const int elem = threadIdx.x;                    // float4 index within row
    const int total = cum[BB];                       // ragged total rows (<= 32768)

    // Each block-iteration handles one full 4KB output row: 256 threads x 16B.
    for (int task = blockIdx.x; task < NTASKS; task += gridDim.x) {
        const int  row   = task & (MAX_TOTAL - 1);
        const bool is_k  = (task < MAX_TOTAL);
        const float4* __restrict__ in  = is_k ? kin  : vin;
        float4* __restrict__       out = is_k ? kout : vout;

        float4 val = zero;
        if (row < total) {
            // Find owning batch: block-uniform 7-step scan over cumsum.
            int b = 0;
#pragma unroll
            for (int i = 1; i < BB; ++i) b += (row >= cum[i]);
            const int t = row - cum[b];
            val = in[((size_t)b * SS + (size_t)t) * ROW_F4 + elem];
        }
        out[(size_t)row * ROW_F4 + elem] = val;
    }
}

extern "C" void kernel_launch(void* const* d_in, const int* in_sizes, int n_in,
                              void* d_out, int out_size, void* d_ws, size_t ws_size,
                              hipStream_t stream) {
    const float4* kin = (const float4*)d_in[0];
    const float4* vin = (const float4*)d_in[1];
    const int*    seq = (const int*)d_in[2];

    float* out = (float*)d_out;
    const size_t NK = (size_t)MAX_TOTAL * 1024;   // floats per cache
    float4* kout = (float4*)out;
    float4* vout = (float4*)(out + NK);
    float*  meta = out + 2 * NK;                  // 8 seq_lens + 9 cumsum

    hipLaunchKernelGGL(pack_kv_kernel, dim3(2048), dim3(256), 0, stream,
                       kin, vin, seq, kout, vout, meta);
}

// Round 3
// 410.448 us; speedup vs baseline: 1.0108x; 1.0108x over previous
//
#include <hip/hip_runtime.h>

// Problem constants: B=8, S=4096, H=8, D=128
// MAX_TOTAL = B*S = 32768 output cache rows per cache; row = 1024 f32 = 4 KB.
#define BB 8
#define SS 4096
#define ROW_F4 256             // float4 per row
#define MAX_TOTAL 32768
#define NTASKS (2 * MAX_TOTAL) // k rows then v rows
#define GRID 2048              // must divide NTASKS/4 exactly (65536 = 8*4*2048)

// True clang vector type: __builtin_nontemporal_* requires scalar/vector
// pointee, not HIP's HIP_vector_type struct.
typedef float f32x4 __attribute__((ext_vector_type(4)));

__global__ __launch_bounds__(256) void pack_kv_kernel(
    const f32x4* __restrict__ kin,
    const f32x4* __restrict__ vin,
    const int*   __restrict__ seq,
    f32x4* __restrict__ kout,
    f32x4* __restrict__ vout,
    float* __restrict__ meta)   // meta[0..7]=seq_lens, meta[8..16]=cumsum(9)
{
    // Tiny uniform cumsum in SGPRs (seq is 8 ints, L2-hot, scalar loads).
    int cum[BB + 1];
    cum[0] = 0;
#pragma unroll
    for (int b = 0; b < BB; ++b) cum[b + 1] = cum[b] + seq[b];

    if (blockIdx.x == 0 && threadIdx.x < (BB + BB + 1)) {
        int t = threadIdx.x;
        if (t < BB) meta[t] = (float)seq[t];
        else        meta[t] = (float)cum[t - BB];   // meta[8+i] = cum[i]
    }

    const f32x4 zero = (f32x4)(0.f);
    const int elem  = threadIdx.x;   // float4 index within the 4 KB row
    const int total = cum[BB];       // ragged total rows (<= 32768)
    const int g     = gridDim.x;     // == GRID

    // 4-way unrolled grid-stride loop: issue 4 independent 16B loads, THEN
    // 4 stores -> 4 KB outstanding per wave instead of 1 KB (MLP for the
    // dependent load->store copy path). 65536 tasks / (4*2048) = 8 iters, no tail.
    for (int t0 = blockIdx.x; t0 < NTASKS; t0 += 4 * g) {
        f32x4 v[4];
#pragma unroll
        for (int u = 0; u < 4; ++u) {
            const int task = t0 + u * g;
            const int row  = task & (MAX_TOTAL - 1);
            v[u] = zero;
            if (row < total) {
                const f32x4* __restrict__ in = (task < MAX_TOTAL) ? kin : vin;
                int b = 0;
#pragma unroll
                for (int i = 1; i < BB; ++i) b += (row >= cum[i]);
                const int t = row - cum[b];
                v[u] = __builtin_nontemporal_load(
                    &in[((size_t)b * SS + (size_t)t) * ROW_F4 + elem]);
            }
        }
#pragma unroll
        for (int u = 0; u < 4; ++u) {
            const int task = t0 + u * g;
            const int row  = task & (MAX_TOTAL - 1);
            f32x4* __restrict__ out = (task < MAX_TOTAL) ? kout : vout;
            __builtin_nontemporal_store(v[u], &out[(size_t)row * ROW_F4 + elem]);
        }
    }
}

extern "C" void kernel_launch(void* const* d_in, const int* in_sizes, int n_in,
                              void* d_out, int out_size, void* d_ws, size_t ws_size,
                              hipStream_t stream) {
    const f32x4* kin = (const f32x4*)d_in[0];
    const f32x4* vin = (const f32x4*)d_in[1];
    const int*   seq = (const int*)d_in[2];

    float* out = (float*)d_out;
    const size_t NK = (size_t)MAX_TOTAL * 1024;   // floats per cache
    f32x4* kout = (f32x4*)out;
    f32x4* vout = (f32x4*)(out + NK);
    float* meta = out + 2 * NK;                   // 8 seq_lens + 9 cumsum

    hipLaunchKernelGGL(pack_kv_kernel, dim3(GRID), dim3(256), 0, stream,
                       kin, vin, seq, kout, vout, meta);
}